// Round 11
// baseline (55.880 us; speedup 1.0000x reference)
//
#include <hip/hip_runtime.h>
#include <math.h>

// GptOssTopKRouter on MI355X — round 11: r10 structure + X-prefetch depth 4.
//
// r7/r9/r10 all land 52-56us across wildly different structures while every
// pipe sits at 15-25% util -> latency-bound with ~2-step load lead being the
// shared invariant. Single change this round: 4-phase unrolled main loop with
// four named X register buffers (depth-4 X prefetch, ~14 dwordx4 in flight
// per wave) while W stays depth-2. Everything else identical to round 10:
//   - logits^T = W[32,2880] @ X^T, 6 bf16 MFMA passes of 3-term trunc split
//     (hh,mh,lh,hm,mm,hl -> logit err ~2e-7, tie-safe top-4; r8's 2-term
//     flipped a near-tie).
//   - 32x32x16 MFMA: 32 experts = one A-tile, 32 tokens = one B-tile;
//     B-frag (col=lane&31=token, k=(lane>>5)*8+j) == X row-major slice ->
//     in-register split, zero LDS staging, zero main-loop barriers.
//   - W pre-split + fragment-packed by wb_kernel (590 KB, L2-resident).
//   - wave = 32 tokens x K-eighth (24 k16-steps, K padded 180->192, pad W=0,
//     X addr clamped); block = 8 waves, TPB=32, grid 512 -> 4 waves/SIMD.

#define HIDDEN 2880
#define NE 32
#define TOPK 4
#define TPB 32            // tokens per block
#define NK16 192          // padded k16 steps (180 real + 12 zero)
#define RK16 180          // real k16 steps
#define VS (NK16 * 512)   // ver stride in wb: 98304 shorts

typedef __attribute__((ext_vector_type(8)))  short bf16x8;
typedef __attribute__((ext_vector_type(16))) float f32x16;

#define MFMA32(a, b, c) __builtin_amdgcn_mfma_f32_32x32x16_bf16((a), (b), (c), 0, 0, 0)

// Pre-kernel: W[32][2880] fp32 -> WB[3 ver][192 ks][512] bf16, exact 32x32
// A-fragment order: elem (l,j) = split_ver(W[l&31][ks*16 + (l>>5)*8 + j]);
// ks >= 180 slots are zero.
__global__ void wb_kernel(const float* __restrict__ w, unsigned short* __restrict__ wb) {
    int i = blockIdx.x * 256 + threadIdx.x;
    if (i >= 3 * VS) return;
    int j = i & 7;
    int l = (i >> 3) & 63;
    int rest = i >> 9;
    int ks  = rest % NK16;
    int ver = rest / NK16;
    unsigned short outv = 0;
    if (ks < RK16) {
        int e = l & 31;
        int k = ks * 16 + (l >> 5) * 8 + j;
        float v = w[e * HIDDEN + k];
        unsigned u = __float_as_uint(v);
        unsigned h = u >> 16;
        float r = v - __uint_as_float(u & 0xffff0000u);          // exact
        unsigned ur = __float_as_uint(r);
        unsigned m = ur >> 16;
        float r2 = r - __uint_as_float(ur & 0xffff0000u);        // exact
        unsigned lo = __float_as_uint(r2) >> 16;
        outv = (unsigned short)(ver == 0 ? h : (ver == 1 ? m : lo));
    }
    wb[i] = outv;
}

// split 8 consecutive fp32 -> 3 bf16x8 (hi, mid, lo), fully in-register
__device__ __forceinline__ void split24(float4 a, float4 b,
                                        bf16x8& H, bf16x8& M, bf16x8& L) {
    union { bf16x8 v; unsigned u[4]; } h, m, l;
    float f[8] = {a.x, a.y, a.z, a.w, b.x, b.y, b.z, b.w};
    unsigned hh[8], mm[8], ll[8];
#pragma unroll
    for (int i = 0; i < 8; ++i) {
        unsigned u = __float_as_uint(f[i]);
        hh[i] = u >> 16;
        float r = f[i] - __uint_as_float(u & 0xffff0000u);       // exact
        unsigned ur = __float_as_uint(r);
        mm[i] = ur >> 16;
        float r2 = r - __uint_as_float(ur & 0xffff0000u);        // exact
        ll[i] = __float_as_uint(r2) >> 16;
    }
#pragma unroll
    for (int i = 0; i < 4; ++i) {
        h.u[i] = hh[2 * i] | (hh[2 * i + 1] << 16);
        m.u[i] = mm[2 * i] | (mm[2 * i + 1] << 16);
        l.u[i] = ll[2 * i] | (ll[2 * i + 1] << 16);
    }
    H = h.v; M = m.v; L = l.v;
}

__global__ __launch_bounds__(512, 4)
void router_kernel(const float* __restrict__ x,
                   const unsigned short* __restrict__ wb,
                   const float* __restrict__ bias,
                   float* __restrict__ out_scores,
                   float* __restrict__ out_idx)
{
    __shared__ float part[8][TPB][36];    // 36.9 KB: per-wave K-eighth partials
    __shared__ float score[TPB][33];      //  4.2 KB: score stash

    const int tid  = threadIdx.x;
    const int lane = tid & 63;
    const int w    = tid >> 6;        // K-eighth 0..7
    const int col  = lane & 31;       // token within block (= B-frag col)
    const int kg   = lane >> 5;       // k sub-group (= frag k group)

    const float* xrow = x + (size_t)(blockIdx.x * TPB + col) * HIDDEN + kg * 8;
    const unsigned short* wk = wb + lane * 8;

    f32x16 acc = {0.f};               // 32 experts x token col

#define LOADX(A0, A1, sg) do {                                                    \
    const int sx_ = min((sg), RK16 - 1);                                          \
    A0 = *(const float4*)(xrow + (size_t)sx_ * 16);                               \
    A1 = *(const float4*)(xrow + (size_t)sx_ * 16 + 4);                           \
} while (0)

#define LOADW(W3, sg) do {                                                        \
    const unsigned short* p_ = wk + (size_t)min((sg), NK16 - 1) * 512;            \
    W3[0] = *(const bf16x8*)(p_);              /* hi  */                          \
    W3[1] = *(const bf16x8*)(p_ + VS);         /* mid */                          \
    W3[2] = *(const bf16x8*)(p_ + 2 * VS);     /* lo  */                          \
} while (0)

#define MFMA6(W3, XH, XM, XL) do {                                                \
    acc = MFMA32(W3[0], XH, acc);                                                 \
    acc = MFMA32(W3[1], XH, acc);                                                 \
    acc = MFMA32(W3[2], XH, acc);                                                 \
    acc = MFMA32(W3[0], XM, acc);                                                 \
    acc = MFMA32(W3[1], XM, acc);                                                 \
    acc = MFMA32(W3[0], XL, acc);                                                 \
} while (0)

// phase: consume X buffer XB (step s+P), reload it for step s+P+4;
//        consume W buffer WB3 (step s+P), reload it for step s+P+2.
#define PHASE(XB0, XB1, WB3, s, P) do {                                           \
    bf16x8 xh_, xm_, xl_;                                                         \
    split24(XB0, XB1, xh_, xm_, xl_);                                             \
    LOADX(XB0, XB1, (s) + (P) + 4);                                               \
    MFMA6(WB3, xh_, xm_, xl_);                                                    \
    LOADW(WB3, (s) + (P) + 2);                                                    \
} while (0)

    const int sg0 = w * 24;
    float4 x0a, x0b, x1a, x1b, x2a, x2b, x3a, x3b;
    bf16x8 Wa[3], Wb[3];
    LOADX(x0a, x0b, sg0);
    LOADX(x1a, x1b, sg0 + 1);
    LOADX(x2a, x2b, sg0 + 2);
    LOADX(x3a, x3b, sg0 + 3);
    LOADW(Wa, sg0);
    LOADW(Wb, sg0 + 1);

#pragma unroll 1
    for (int i = 0; i < 6; ++i) {             // 6 iters x 4 phases = 24 k16-steps
        const int s = sg0 + 4 * i;
        PHASE(x0a, x0b, Wa, s, 0);
        PHASE(x1a, x1b, Wb, s, 1);
        PHASE(x2a, x2b, Wa, s, 2);
        PHASE(x3a, x3b, Wb, s, 3);
    }

#undef LOADX
#undef LOADW
#undef MFMA6
#undef PHASE

    // ---- C/D layout (m74/m101-verified 32x32): col=lane&31=token,
    //      row=(reg&3)+8*(reg>>2)+4*(lane>>5)=expert ----
#pragma unroll
    for (int r = 0; r < 16; ++r)
        part[w][col][(r & 3) + 8 * (r >> 2) + 4 * kg] = acc[r];
    __syncthreads();

    // ---- top-4 + softmax, one lane per token ----
    if (tid < TPB) {
        float lg[NE];
#pragma unroll
        for (int e = 0; e < NE; ++e) {
            float s = bias[e];
#pragma unroll
            for (int p = 0; p < 8; ++p) s += part[p][tid][e];
            lg[e] = s;
        }

        float vals[TOPK]; int idxs[TOPK]; unsigned chosen = 0u;
#pragma unroll
        for (int k = 0; k < TOPK; ++k) {
            float m = -INFINITY; int mi = 0;
#pragma unroll
            for (int e = 0; e < NE; ++e) {
                const bool take = (((chosen >> e) & 1u) == 0u) && (lg[e] > m);
                m  = take ? lg[e] : m;
                mi = take ? e : mi;
            }
            vals[k] = m; idxs[k] = mi; chosen |= (1u << (unsigned)mi);
        }
        const float mx = vals[0];
        float p[TOPK]; float sum = 0.f;
#pragma unroll
        for (int k = 0; k < TOPK; ++k) { p[k] = __expf(vals[k] - mx); sum += p[k]; }
        const float inv = 1.0f / sum;
#pragma unroll
        for (int e = 0; e < NE; ++e) {
            float v = 0.f;
#pragma unroll
            for (int k = 0; k < TOPK; ++k) v = (e == idxs[k]) ? p[k] * inv : v;
            score[tid][e] = v;
        }
        const int t = blockIdx.x * TPB + tid;
        float4 iv = make_float4((float)idxs[0], (float)idxs[1], (float)idxs[2], (float)idxs[3]);
        *reinterpret_cast<float4*>(out_idx + (size_t)t * TOPK) = iv;
    }
    __syncthreads();

    // ---- coalesced score store: 1024 floats, 512 threads x float2 ----
    {
        const int f = tid * 2;
        const int t = f >> 5, e = f & 31;
        float2 v = make_float2(score[t][e], score[t][e + 1]);
        *reinterpret_cast<float2*>(out_scores + (size_t)blockIdx.x * TPB * NE + f) = v;
    }
}

extern "C" void kernel_launch(void* const* d_in, const int* in_sizes, int n_in,
                              void* d_out, int out_size, void* d_ws, size_t ws_size,
                              hipStream_t stream)
{
    const float* x = (const float*)d_in[0];
    const float* w = (const float*)d_in[1];
    const float* b = (const float*)d_in[2];
    const int T = in_sizes[0] / HIDDEN;            // 16384 tokens

    unsigned short* wbuf = (unsigned short*)d_ws;  // 3*192*512 bf16 = 590 KB
    float* out        = (float*)d_out;
    float* out_scores = out;                       // [T, 32]
    float* out_idx    = out + (size_t)T * NE;      // [T, 4] as fp32 values

    wb_kernel<<<dim3((3 * VS + 255) / 256), dim3(256), 0, stream>>>(w, wbuf);
    router_kernel<<<dim3(T / TPB), dim3(512), 0, stream>>>(x, wbuf, b, out_scores, out_idx);
}